// Round 1
// baseline (19.868 us; speedup 1.0000x reference)
//
#include <hip/hip_runtime.h>
#include <math.h>

#define VOCAB 5
#define DIM   64
#define BATCH 8
#define SLEN  2048
#define SEG   256
#define NSEG  (SLEN / SEG)   // 8
#define BLOCK 256

// ws layout (floats): [0..25) Stab (scale folded in), [32..352) Vtab

__global__ void tabs_kernel(const float* __restrict__ emb,
                            const float* __restrict__ wq, const float* __restrict__ bq,
                            const float* __restrict__ wk, const float* __restrict__ bk,
                            const float* __restrict__ wv, const float* __restrict__ bv,
                            float* __restrict__ ws) {
    __shared__ float eSh[VOCAB * DIM];
    __shared__ float qSh[VOCAB * DIM];
    __shared__ float kSh[VOCAB * DIM];
    int t = threadIdx.x;                 // 320 threads
    if (t < VOCAB * DIM) eSh[t] = emb[t];
    __syncthreads();
    if (t < VOCAB * DIM) {
        int v = t >> 6, d = t & 63;
        float q = bq[d], k = bk[d], vv = bv[d];
        for (int i = 0; i < DIM; ++i) {
            float e = eSh[v * DIM + i];
            q  += e * wq[d * DIM + i];   // torch Linear: y = x @ W.T + b
            k  += e * wk[d * DIM + i];
            vv += e * wv[d * DIM + i];
        }
        qSh[t] = q;
        kSh[t] = k;
        ws[32 + t] = vv;                 // Vtab
    }
    __syncthreads();
    if (t < VOCAB * VOCAB) {
        int i = t / VOCAB, j = t % VOCAB;
        float s = 0.f;
        for (int d = 0; d < DIM; ++d) s += qSh[i * DIM + d] * kSh[j * DIM + d];
        ws[t] = s * 0.125f;              // * 1/sqrt(64)
    }
}

__global__ __launch_bounds__(BLOCK) void attn_kernel(const int* __restrict__ x,
                                                     const float* __restrict__ ws,
                                                     float* __restrict__ out) {
    const int b   = blockIdx.x >> 3;     // NSEG == 8
    const int seg = blockIdx.x & 7;
    const int s0  = seg * SEG;
    const int t    = threadIdx.x;
    const int lane = t & 63;
    const int wave = t >> 6;

    __shared__ float StabSh[VOCAB * VOCAB];
    __shared__ float ESh[VOCAB * VOCAB];
    __shared__ __align__(16) float Vs[VOCAB * DIM];
    __shared__ float p[SEG * VOCAB];
    __shared__ int baseSh[VOCAB];
    __shared__ int waveCnt[BLOCK / 64][VOCAB];

    if (t < VOCAB) baseSh[t] = 0;
    if (t < VOCAB * VOCAB) StabSh[t] = ws[t];
    for (int i = t; i < VOCAB * DIM; i += BLOCK) Vs[i] = ws[32 + i];
    __syncthreads();

    if (t < VOCAB * VOCAB) {
        int row = t / VOCAB;
        float mx = StabSh[row * VOCAB];
        for (int j = 1; j < VOCAB; ++j) mx = fmaxf(mx, StabSh[row * VOCAB + j]);
        ESh[t] = expf(StabSh[t] - mx);
    }

    // base counts: occurrences of each vocab in x[b, 0 .. s0)
    const int* xb = x + b * SLEN;
    for (int i = t; i < s0; i += BLOCK) atomicAdd(&baseSh[xb[i]], 1);

    // within-segment inclusive prefix counts via ballot
    const int tok = xb[s0 + t];
    const unsigned long long leMask = (2ull << lane) - 1ull;  // lanes <= me
    int inc[VOCAB];
    #pragma unroll
    for (int v = 0; v < VOCAB; ++v) {
        unsigned long long m = __ballot(tok == v);
        inc[v] = __popcll(m & leMask);
        if (lane == 0) waveCnt[wave][v] = __popcll(m);
    }
    __syncthreads();

    float w[VOCAB];
    float den = 0.f;
    #pragma unroll
    for (int v = 0; v < VOCAB; ++v) {
        int c = baseSh[v] + inc[v];
        for (int pw = 0; pw < wave; ++pw) c += waveCnt[pw][v];
        float wv = (float)c * ESh[tok * VOCAB + v];
        w[v] = wv;
        den += wv;
    }
    const float inv = 1.0f / den;
    #pragma unroll
    for (int v = 0; v < VOCAB; ++v) p[t * VOCAB + v] = w[v] * inv;
    __syncthreads();

    // phase 2: coalesced float4 output, out[b, s0+q, :] = sum_v p[q][v] * Vtab[v][:]
    const float4* Vs4 = reinterpret_cast<const float4*>(Vs);
    float4* out4 = reinterpret_cast<float4*>(out) + ((size_t)b * SLEN + s0) * (DIM / 4);
    for (int i = t; i < SEG * (DIM / 4); i += BLOCK) {
        int q = i >> 4, d4 = i & 15;
        float4 acc = make_float4(0.f, 0.f, 0.f, 0.f);
        #pragma unroll
        for (int v = 0; v < VOCAB; ++v) {
            float pw = p[q * VOCAB + v];
            float4 vv = Vs4[v * (DIM / 4) + d4];
            acc.x += pw * vv.x;
            acc.y += pw * vv.y;
            acc.z += pw * vv.z;
            acc.w += pw * vv.w;
        }
        out4[i] = acc;
    }
}

extern "C" void kernel_launch(void* const* d_in, const int* in_sizes, int n_in,
                              void* d_out, int out_size, void* d_ws, size_t ws_size,
                              hipStream_t stream) {
    const int*   x   = (const int*)d_in[0];
    const float* emb = (const float*)d_in[1];
    const float* wq  = (const float*)d_in[2];
    const float* bq  = (const float*)d_in[3];
    const float* wk  = (const float*)d_in[4];
    const float* bk  = (const float*)d_in[5];
    const float* wv  = (const float*)d_in[6];
    const float* bv  = (const float*)d_in[7];
    float* out = (float*)d_out;
    float* ws  = (float*)d_ws;

    tabs_kernel<<<1, VOCAB * DIM, 0, stream>>>(emb, wq, bq, wk, bk, wv, bv, ws);
    attn_kernel<<<BATCH * NSEG, BLOCK, 0, stream>>>(x, ws, out);
}

// Round 2
// 12.343 us; speedup vs baseline: 1.6096x; 1.6096x over previous
//
#include <hip/hip_runtime.h>
#include <math.h>

#define VOCAB 5
#define DIM   64
#define BATCH 8
#define SLEN  2048
#define SEG   64
#define SEGS_PER_B (SLEN / SEG)   // 32
#define BLOCK 256
#define WPAD  65                  // pad 64->65: lane d reads bank (d+i)%32, conflict-free

__global__ __launch_bounds__(BLOCK) void decoder_fused(
    const int* __restrict__ x, const float* __restrict__ emb,
    const float* __restrict__ wq, const float* __restrict__ bq,
    const float* __restrict__ wk, const float* __restrict__ bk,
    const float* __restrict__ wv, const float* __restrict__ bv,
    float* __restrict__ out)
{
    const int bid  = blockIdx.x;
    const int b    = bid >> 5;           // SEGS_PER_B == 32
    const int seg  = bid & 31;
    const int s0   = seg * SEG;
    const int t    = threadIdx.x;
    const int lane = t & 63;
    const int wave = t >> 6;

    __shared__ float wSh[3][DIM * WPAD];          // 49,920 B
    __shared__ float eSh[VOCAB * DIM];
    __shared__ float qSh[VOCAB * DIM];
    __shared__ float kSh[VOCAB * DIM];
    __shared__ __align__(16) float vSh[VOCAB * DIM];
    __shared__ float StabSh[VOCAB * VOCAB];
    __shared__ float ESh[VOCAB * VOCAB];
    __shared__ float pSh[SEG * VOCAB];
    __shared__ int   waveCnt[4][VOCAB];

    // ---- stage weights into padded LDS (coalesced float4 global reads) ----
    {
        const float4* wq4 = (const float4*)wq;
        const float4* wk4 = (const float4*)wk;
        const float4* wv4 = (const float4*)wv;
        for (int j = t; j < DIM * DIM / 4; j += BLOCK) {
            int d = j >> 4, i4 = (j & 15) << 2;
            float4 a = wq4[j], c = wk4[j], e = wv4[j];
            float* dq = &wSh[0][d * WPAD + i4];
            float* dk = &wSh[1][d * WPAD + i4];
            float* dv = &wSh[2][d * WPAD + i4];
            dq[0]=a.x; dq[1]=a.y; dq[2]=a.z; dq[3]=a.w;
            dk[0]=c.x; dk[1]=c.y; dk[2]=c.z; dk[3]=c.w;
            dv[0]=e.x; dv[1]=e.y; dv[2]=e.z; dv[3]=e.w;
        }
        for (int i = t; i < VOCAB * DIM; i += BLOCK) eSh[i] = emb[i];
    }
    __syncthreads();

    // ---- Q/K/V tables: 320 dot-products of length 64 each ----
    for (int idx = t; idx < VOCAB * DIM; idx += BLOCK) {
        int v = idx >> 6, d = idx & 63;
        float aq = bq[d], ak = bk[d], av = bv[d];
        const float* e  = &eSh[v * DIM];
        const float* rq = &wSh[0][d * WPAD];
        const float* rk = &wSh[1][d * WPAD];
        const float* rv = &wSh[2][d * WPAD];
        #pragma unroll 16
        for (int i = 0; i < DIM; ++i) {
            float ei = e[i];
            aq += ei * rq[i];
            ak += ei * rk[i];
            av += ei * rv[i];
        }
        qSh[idx] = aq; kSh[idx] = ak; vSh[idx] = av;
    }
    __syncthreads();

    // ---- 5x5 score table + exp table ----
    if (t < VOCAB * VOCAB) {
        int i = t / VOCAB, j = t % VOCAB;
        float s = 0.f;
        #pragma unroll
        for (int d = 0; d < DIM; ++d) s += qSh[i * DIM + d] * kSh[j * DIM + d];
        StabSh[t] = s * 0.125f;              // * 1/sqrt(64)
    }
    __syncthreads();
    if (t < VOCAB * VOCAB) {
        int row = t / VOCAB;
        float mx = StabSh[row * VOCAB];
        #pragma unroll
        for (int j = 1; j < VOCAB; ++j) mx = fmaxf(mx, StabSh[row * VOCAB + j]);
        ESh[t] = expf(StabSh[t] - mx);
    }

    // ---- causal prefix counts via ballots (no atomics) ----
    const int* xb = x + b * SLEN;
    int base[VOCAB] = {0,0,0,0,0};
    const int nchunk = s0 >> 6;              // 64-wide chunks before this segment
    for (int c = wave; c < nchunk; c += 4) {
        int tk = xb[(c << 6) + lane];
        #pragma unroll
        for (int v = 0; v < VOCAB; ++v)
            base[v] += __popcll(__ballot(tk == v));
    }
    if (lane == 0) {
        #pragma unroll
        for (int v = 0; v < VOCAB; ++v) waveCnt[wave][v] = base[v];
    }
    // in-segment inclusive counts (all 4 waves redundantly; lane == position)
    const int tok = xb[s0 + lane];
    const unsigned long long leMask = (2ull << lane) - 1ull;  // lane 63 -> all ones
    int inc[VOCAB];
    #pragma unroll
    for (int v = 0; v < VOCAB; ++v)
        inc[v] = __popcll(__ballot(tok == v) & leMask);
    __syncthreads();   // covers waveCnt + ESh + vSh visibility

    // ---- per-position softmax weights (5 terms) ----
    if (t < SEG) {     // wave 0, lane t == position t
        float wgt[VOCAB];
        float den = 0.f;
        #pragma unroll
        for (int v = 0; v < VOCAB; ++v) {
            int c = inc[v] + waveCnt[0][v] + waveCnt[1][v] + waveCnt[2][v] + waveCnt[3][v];
            float wv = (float)c * ESh[tok * VOCAB + v];
            wgt[v] = wv;
            den += wv;
        }
        float invd = 1.0f / den;
        #pragma unroll
        for (int v = 0; v < VOCAB; ++v) pSh[t * VOCAB + v] = wgt[v] * invd;
    }
    __syncthreads();

    // ---- output: out[b, s0+q, :] = sum_v p[q][v] * Vtab[v][:], float4 coalesced ----
    const float4* Vs4 = reinterpret_cast<const float4*>(vSh);
    float4* out4 = reinterpret_cast<float4*>(out) + ((size_t)b * SLEN + s0) * (DIM / 4);
    for (int i = t; i < SEG * (DIM / 4); i += BLOCK) {   // 4 iterations
        int q = i >> 4, d4 = i & 15;
        float4 acc = make_float4(0.f, 0.f, 0.f, 0.f);
        #pragma unroll
        for (int v = 0; v < VOCAB; ++v) {
            float pw = pSh[q * VOCAB + v];
            float4 vv = Vs4[v * (DIM / 4) + d4];
            acc.x += pw * vv.x;
            acc.y += pw * vv.y;
            acc.z += pw * vv.z;
            acc.w += pw * vv.w;
        }
        out4[i] = acc;
    }
}

extern "C" void kernel_launch(void* const* d_in, const int* in_sizes, int n_in,
                              void* d_out, int out_size, void* d_ws, size_t ws_size,
                              hipStream_t stream) {
    const int*   x   = (const int*)d_in[0];
    const float* emb = (const float*)d_in[1];
    const float* wq  = (const float*)d_in[2];
    const float* bq  = (const float*)d_in[3];
    const float* wk  = (const float*)d_in[4];
    const float* bk  = (const float*)d_in[5];
    const float* wv  = (const float*)d_in[6];
    const float* bv  = (const float*)d_in[7];
    float* out = (float*)d_out;

    decoder_fused<<<BATCH * SEGS_PER_B, BLOCK, 0, stream>>>(
        x, emb, wq, bq, wk, bk, wv, bv, out);
}

// Round 3
// 11.108 us; speedup vs baseline: 1.7886x; 1.1112x over previous
//
#include <hip/hip_runtime.h>
#include <math.h>

#define VOCAB 5
#define DIM   64
#define BATCH 8
#define SLEN  2048
#define SEG   64
#define SEGS_PER_B (SLEN / SEG)   // 32
#define BLOCK 512
#define WPAD  65                  // pad 64->65: row-major column reads are conflict-free

__global__ __launch_bounds__(BLOCK) void decoder_fused(
    const int* __restrict__ x, const float* __restrict__ emb,
    const float* __restrict__ wq, const float* __restrict__ bq,
    const float* __restrict__ wk, const float* __restrict__ bk,
    const float* __restrict__ wv, const float* __restrict__ bv,
    float* __restrict__ out)
{
    const int bid  = blockIdx.x;
    const int b    = bid >> 5;           // SEGS_PER_B == 32
    const int seg  = bid & 31;
    const int s0   = seg * SEG;
    const int t    = threadIdx.x;
    const int lane = t & 63;
    const int wave = t >> 6;

    __shared__ float wSh[3][DIM * WPAD];           // 48.75 KB
    __shared__ float eSh[VOCAB * DIM];
    __shared__ float qSh[VOCAB * WPAD];
    __shared__ float kSh[VOCAB * WPAD];
    __shared__ __align__(16) float vSh[VOCAB * DIM];
    __shared__ float StabSh[VOCAB * VOCAB];
    __shared__ float pSh[SEG * VOCAB];
    __shared__ int   wcSh[4][VOCAB];

    const int* xb = x + b * SLEN;

    int tok = 0;
    int inc[VOCAB] = {0, 0, 0, 0, 0};

    if (wave < 4) {
        // ---- waves 0-3: stage weights into padded LDS (float4 global reads) ----
        const float4* wq4 = (const float4*)wq;
        const float4* wk4 = (const float4*)wk;
        const float4* wv4 = (const float4*)wv;
        for (int j = t; j < DIM * DIM / 4; j += 256) {
            int d = j >> 4, i4 = (j & 15) << 2;
            float4 a = wq4[j];
            float* dst = &wSh[0][d * WPAD + i4];
            dst[0] = a.x; dst[1] = a.y; dst[2] = a.z; dst[3] = a.w;
        }
        for (int j = t; j < DIM * DIM / 4; j += 256) {
            int d = j >> 4, i4 = (j & 15) << 2;
            float4 a = wk4[j];
            float* dst = &wSh[1][d * WPAD + i4];
            dst[0] = a.x; dst[1] = a.y; dst[2] = a.z; dst[3] = a.w;
        }
        for (int j = t; j < DIM * DIM / 4; j += 256) {
            int d = j >> 4, i4 = (j & 15) << 2;
            float4 a = wv4[j];
            float* dst = &wSh[2][d * WPAD + i4];
            dst[0] = a.x; dst[1] = a.y; dst[2] = a.z; dst[3] = a.w;
        }
    } else {
        // ---- waves 4-7: emb staging + causal prefix counts (overlaps staging) ----
        for (int i = t - 256; i < VOCAB * DIM; i += 256) eSh[i] = emb[i];

        const int pw = wave - 4;
        int base[VOCAB] = {0, 0, 0, 0, 0};
        const int nchunk = s0 >> 6;          // 64-wide chunks before this segment
        for (int c = pw; c < nchunk; c += 4) {
            int tk = xb[(c << 6) + lane];
            #pragma unroll
            for (int v = 0; v < VOCAB; ++v)
                base[v] += __popcll(__ballot(tk == v));
        }
        if (lane == 0) {
            #pragma unroll
            for (int v = 0; v < VOCAB; ++v) wcSh[pw][v] = base[v];
        }
        if (wave == 7) {
            // in-segment inclusive counts; lane == position within segment
            tok = xb[s0 + lane];
            const unsigned long long leMask = (2ull << lane) - 1ull;
            #pragma unroll
            for (int v = 0; v < VOCAB; ++v)
                inc[v] = __popcll(__ballot(tok == v) & leMask);
        }
    }
    __syncthreads();   // B1: weights + emb staged, counts in wcSh / regs

    // ---- waves 0-4: Q/K/V tables, one vocab per wave, lane = d ----
    if (wave < 5) {
        const int v = wave, d = lane;
        float aq = bq[d], ak = bk[d], av = bv[d];
        const float* e  = &eSh[v * DIM];        // wave-uniform broadcast reads
        const float* rq = &wSh[0][d * WPAD];    // (d+i) % 32 banks: conflict-free
        const float* rk = &wSh[1][d * WPAD];
        const float* rv = &wSh[2][d * WPAD];
        #pragma unroll 16
        for (int i = 0; i < DIM; ++i) {
            float ei = e[i];
            aq += ei * rq[i];
            ak += ei * rk[i];
            av += ei * rv[i];
        }
        qSh[v * WPAD + d] = aq;
        kSh[v * WPAD + d] = ak;
        vSh[v * DIM + d]  = av;
    }
    __syncthreads();   // B2: q/k/v tables ready

    // ---- 5x5 score table (25 lanes of wave 0, conflict-free via WPAD) ----
    if (t < VOCAB * VOCAB) {
        int i = t / VOCAB, j = t % VOCAB;
        float s = 0.f;
        #pragma unroll 16
        for (int d = 0; d < DIM; ++d)
            s += qSh[i * WPAD + d] * kSh[j * WPAD + d];
        StabSh[t] = s * 0.125f;               // * 1/sqrt(64)
    }
    __syncthreads();   // B3: Stab ready

    // ---- wave 7: per-position softmax weights, exp in registers ----
    if (wave == 7) {
        float sv[VOCAB];
        #pragma unroll
        for (int v = 0; v < VOCAB; ++v) sv[v] = StabSh[tok * VOCAB + v];
        float mx = fmaxf(fmaxf(fmaxf(sv[0], sv[1]), fmaxf(sv[2], sv[3])), sv[4]);
        float wgt[VOCAB];
        float den = 0.f;
        #pragma unroll
        for (int v = 0; v < VOCAB; ++v) {
            int c = inc[v] + wcSh[0][v] + wcSh[1][v] + wcSh[2][v] + wcSh[3][v];
            float wv = (float)c * expf(sv[v] - mx);
            wgt[v] = wv;
            den += wv;
        }
        float invd = 1.0f / den;
        #pragma unroll
        for (int v = 0; v < VOCAB; ++v) pSh[lane * VOCAB + v] = wgt[v] * invd;
    }
    __syncthreads();   // B4: p ready

    // ---- output: out[b, s0+q, :] = sum_v p[q][v] * Vtab[v][:], float4 coalesced ----
    const float4* Vs4 = reinterpret_cast<const float4*>(vSh);
    float4* out4 = reinterpret_cast<float4*>(out) + ((size_t)b * SLEN + s0) * (DIM / 4);
    for (int i = t; i < SEG * (DIM / 4); i += BLOCK) {   // 2 iterations
        int q = i >> 4, d4 = i & 15;
        float4 acc = make_float4(0.f, 0.f, 0.f, 0.f);
        #pragma unroll
        for (int v = 0; v < VOCAB; ++v) {
            float pw = pSh[q * VOCAB + v];
            float4 vv = Vs4[v * (DIM / 4) + d4];
            acc.x += pw * vv.x;
            acc.y += pw * vv.y;
            acc.z += pw * vv.z;
            acc.w += pw * vv.w;
        }
        out4[i] = acc;
    }
}

extern "C" void kernel_launch(void* const* d_in, const int* in_sizes, int n_in,
                              void* d_out, int out_size, void* d_ws, size_t ws_size,
                              hipStream_t stream) {
    const int*   x   = (const int*)d_in[0];
    const float* emb = (const float*)d_in[1];
    const float* wq  = (const float*)d_in[2];
    const float* bq  = (const float*)d_in[3];
    const float* wk  = (const float*)d_in[4];
    const float* bk  = (const float*)d_in[5];
    const float* wv  = (const float*)d_in[6];
    const float* bv  = (const float*)d_in[7];
    float* out = (float*)d_out;

    decoder_fused<<<BATCH * SEGS_PER_B, BLOCK, 0, stream>>>(
        x, emb, wq, bq, wk, bk, wv, bv, out);
}